// Round 2
// baseline (291.587 us; speedup 1.0000x reference)
//
#include <hip/hip_runtime.h>
#include <hip/hip_bf16.h>

// Head attention, B=8, T=4096, C=512, h=64, prefix-causal mask (j <= max(i,1023)).
// Inputs and output are fp32 (per reference dtypes). Internal q/k/vt are bf16
// (our workspace format) so we can use bf16 MFMA; accumulation is fp32.

typedef short short8 __attribute__((ext_vector_type(8)));   // 8 bf16 = 4 VGPRs
typedef float floatx4 __attribute__((ext_vector_type(4)));

// fp32 -> bf16 RNE
static __device__ __forceinline__ unsigned short f2b(float f) {
  unsigned u = __float_as_uint(f);
  unsigned r = (u + 0x7fffu + ((u >> 16) & 1u)) >> 16;
  return (unsigned short)r;
}

// ---------------------------------------------------------------------------
// Kernel 0: transpose+convert the three [512][64] fp32 weight mats into
// bf16 Wt[3][64][512] so MFMA B-fragments read contiguous k.
__global__ __launch_bounds__(256) void wtrans(
    const float* __restrict__ Wq, const float* __restrict__ Wk,
    const float* __restrict__ Wv, unsigned short* __restrict__ Wt) {
  int m = blockIdx.y;
  const float* W = (m == 0) ? Wq : (m == 1) ? Wk : Wv;
  int idx = blockIdx.x * 256 + threadIdx.x;  // 0..32767, idx = n*512 + k
  int n = idx >> 9;
  int kk = idx & 511;
  Wt[m * 32768 + idx] = f2b(W[kk * 64 + n]);
}

// ---------------------------------------------------------------------------
// Kernel 1: q = x@Wq, k = x@Wk (row-major [32768][64] bf16),
//           vt = (x@Wv)^T per batch ([B][64][4096] bf16).
// One block = 64 rows; wave w owns rows w*16..w*16+15; N=192 (q|k|v).
__global__ __launch_bounds__(256) void proj(
    const float* __restrict__ x, const unsigned short* __restrict__ Wt,
    unsigned short* __restrict__ q, unsigned short* __restrict__ k,
    unsigned short* __restrict__ vt) {
  __shared__ unsigned short Ws[192 * 40];  // [192 n][32 k] padded to 40 (reused as Vl[64][72])

  const int tid = threadIdx.x;
  const int lane = tid & 63;
  const int w = tid >> 6;
  const int m16 = lane & 15;
  const int quad = lane >> 4;
  const int g0 = blockIdx.x * 64;

  floatx4 acc[12];
#pragma unroll
  for (int j = 0; j < 12; ++j) acc[j] = (floatx4)0.0f;

  const int arow = g0 + w * 16 + m16;

  for (int ks = 0; ks < 16; ++ks) {
    __syncthreads();  // previous iteration's B-frag reads done
    // stage Wt[:, ks*32 .. ks*32+31] -> Ws[192][40]
#pragma unroll
    for (int i = 0; i < 3; ++i) {
      int c = tid + i * 256;          // 0..767 chunks of 8
      int n = c >> 2;                 // 0..191
      int kk = (c & 3) * 8;
      short8 val = *reinterpret_cast<const short8*>(&Wt[(unsigned)n * 512 + ks * 32 + kk]);
      *reinterpret_cast<short8*>(&Ws[n * 40 + kk]) = val;
    }
    __syncthreads();
    // A fragment: x[arow][ks*32 + quad*8 .. +7], fp32 -> bf16
    floatx4 x0 = *reinterpret_cast<const floatx4*>(&x[(size_t)arow * 512 + ks * 32 + quad * 8]);
    floatx4 x1 = *reinterpret_cast<const floatx4*>(&x[(size_t)arow * 512 + ks * 32 + quad * 8 + 4]);
    short8 a;
#pragma unroll
    for (int e = 0; e < 4; ++e) { a[e] = (short)f2b(x0[e]); a[4 + e] = (short)f2b(x1[e]); }
#pragma unroll
    for (int j = 0; j < 12; ++j) {
      short8 b = *reinterpret_cast<const short8*>(&Ws[(j * 16 + m16) * 40 + quad * 8]);
      acc[j] = __builtin_amdgcn_mfma_f32_16x16x32_bf16(a, b, acc[j], 0, 0, 0);
    }
  }

  // epilogue: D layout row = quad*4+r (within 16-row m-tile), col = m16
#pragma unroll
  for (int j = 0; j < 4; ++j) {
#pragma unroll
    for (int r = 0; r < 4; ++r) {
      int rr = w * 16 + quad * 4 + r;
      q[(size_t)(g0 + rr) * 64 + j * 16 + m16] = f2b(acc[j][r]);
      k[(size_t)(g0 + rr) * 64 + j * 16 + m16] = f2b(acc[4 + j][r]);
    }
  }
  // v: transpose through LDS, store vt[b][h][t]
  __syncthreads();
  unsigned short* Vl = Ws;  // [64 t][72]
#pragma unroll
  for (int j = 0; j < 4; ++j) {
#pragma unroll
    for (int r = 0; r < 4; ++r) {
      int rr = w * 16 + quad * 4 + r;
      Vl[rr * 72 + j * 16 + m16] = f2b(acc[8 + j][r]);
    }
  }
  __syncthreads();
  const int b = g0 >> 12;
  const int t0 = g0 & 4095;
#pragma unroll
  for (int i = 0; i < 2; ++i) {
    int c = tid + i * 256;  // 0..511
    int h = c >> 3;
    int t8 = (c & 7) * 8;
    unsigned short tmp[8];
#pragma unroll
    for (int e = 0; e < 8; ++e) tmp[e] = Vl[(t8 + e) * 72 + h];
    *reinterpret_cast<short8*>(&vt[(size_t)b * (64 * 4096) + (size_t)h * 4096 + t0 + t8]) =
        *reinterpret_cast<const short8*>(tmp);
  }
}

// ---------------------------------------------------------------------------
// Kernel 2: flash attention. 512 blocks; b = bx&7 (batch->XCD), Q-tile qt paired
// heavy/light across the two resident blocks per CU. 4 waves; wave w owns Q rows
// w*16..w*16+15. Visible cols for row i: j <= max(i, 1023).
__global__ __launch_bounds__(256) void attn(
    const unsigned short* __restrict__ q, const unsigned short* __restrict__ k,
    const unsigned short* __restrict__ vt, float* __restrict__ out) {
  __shared__ unsigned short Ks[64 * 72];  // K tile  [s][h], pad 72
  __shared__ unsigned short Vs[64 * 72];  // V^T tile [h][s], pad 72
  __shared__ unsigned short Ps[64 * 72];  // P (bf16) [q-row][s], per-wave 16-row slabs

  const int tid = threadIdx.x;
  const int lane = tid & 63;
  const int w = tid >> 6;
  const int n16 = lane & 15;
  const int quad = lane >> 4;

  const int bx = blockIdx.x;
  const int b = bx & 7;
  const int i = bx >> 3;
  const int qt = (i < 32) ? i : (95 - i);  // pair qt with 63-qt on same CU

  const unsigned short* qp = q + (size_t)b * 4096 * 64;
  const unsigned short* kp = k + (size_t)b * 4096 * 64;
  const unsigned short* vp = vt + (size_t)b * 64 * 4096;
  float* op = out + (size_t)b * 4096 * 64;
  const int g0 = qt * 64;

  // Q A-fragments, resident for the whole kernel
  short8 qa[2];
#pragma unroll
  for (int ks = 0; ks < 2; ++ks)
    qa[ks] = *reinterpret_cast<const short8*>(
        &qp[(size_t)(g0 + w * 16 + n16) * 64 + ks * 32 + quad * 8]);

  floatx4 O[4];
#pragma unroll
  for (int j = 0; j < 4; ++j) O[j] = (floatx4)0.0f;
  float m_i[4], l_i[4];
#pragma unroll
  for (int r = 0; r < 4; ++r) { m_i[r] = -__builtin_inff(); l_i[r] = 0.0f; }

  // exp2-domain constant: C^-0.5 * log2(e)
  const float cexp = 0.04419417382415922f * 1.4426950408889634f;
  const int ktmax = (qt < 16) ? 15 : qt;

  for (int kt = 0; kt <= ktmax; ++kt) {
    __syncthreads();  // previous tile's consumers done
    // stage K tile and V^T tile
#pragma unroll
    for (int ii = 0; ii < 2; ++ii) {
      int c = tid + ii * 256;
      int rrow = c >> 3;
      int c8 = (c & 7) * 8;
      *reinterpret_cast<short8*>(&Ks[rrow * 72 + c8]) =
          *reinterpret_cast<const short8*>(&kp[(size_t)(kt * 64 + rrow) * 64 + c8]);
      *reinterpret_cast<short8*>(&Vs[rrow * 72 + c8]) =
          *reinterpret_cast<const short8*>(&vp[(size_t)rrow * 4096 + kt * 64 + c8]);
    }
    __syncthreads();

    // S = Q K^T  (raw logits; scale folded into cexp)
    floatx4 S[4];
#pragma unroll
    for (int j = 0; j < 4; ++j) S[j] = (floatx4)0.0f;
#pragma unroll
    for (int ks = 0; ks < 2; ++ks) {
#pragma unroll
      for (int j = 0; j < 4; ++j) {
        short8 bf = *reinterpret_cast<const short8*>(&Ks[(j * 16 + n16) * 72 + ks * 32 + quad * 8]);
        S[j] = __builtin_amdgcn_mfma_f32_16x16x32_bf16(qa[ks], bf, S[j], 0, 0, 0);
      }
    }

    // causal mask, only on the diagonal tile (rows >= 1024)
    if (qt >= 16 && kt == qt) {
#pragma unroll
      for (int j = 0; j < 4; ++j) {
#pragma unroll
        for (int r = 0; r < 4; ++r) {
          int col = j * 16 + n16;
          int rowl = w * 16 + quad * 4 + r;
          if (col > rowl) S[j][r] = -__builtin_inff();
        }
      }
    }

    // online softmax (rows quad*4+r, reduce over 16 lanes of the quad)
    float mnew[4];
#pragma unroll
    for (int r = 0; r < 4; ++r) {
      float mx = fmaxf(fmaxf(S[0][r], S[1][r]), fmaxf(S[2][r], S[3][r]));
      mx = fmaxf(mx, __shfl_xor(mx, 1));
      mx = fmaxf(mx, __shfl_xor(mx, 2));
      mx = fmaxf(mx, __shfl_xor(mx, 4));
      mx = fmaxf(mx, __shfl_xor(mx, 8));
      mnew[r] = fmaxf(m_i[r], mx);
    }
#pragma unroll
    for (int r = 0; r < 4; ++r) {
      float alpha = exp2f((m_i[r] - mnew[r]) * cexp);
      l_i[r] *= alpha;
#pragma unroll
      for (int j = 0; j < 4; ++j) O[j][r] *= alpha;
      m_i[r] = mnew[r];
    }
#pragma unroll
    for (int j = 0; j < 4; ++j)
#pragma unroll
      for (int r = 0; r < 4; ++r)
        S[j][r] = exp2f((S[j][r] - mnew[r]) * cexp);
#pragma unroll
    for (int r = 0; r < 4; ++r) {
      float s = S[0][r] + S[1][r] + S[2][r] + S[3][r];
      s += __shfl_xor(s, 1);
      s += __shfl_xor(s, 2);
      s += __shfl_xor(s, 4);
      s += __shfl_xor(s, 8);
      l_i[r] += s;
    }

    // P (D-layout) -> bf16 -> LDS -> A-layout
#pragma unroll
    for (int j = 0; j < 4; ++j)
#pragma unroll
      for (int r = 0; r < 4; ++r)
        Ps[(w * 16 + quad * 4 + r) * 72 + j * 16 + n16] = f2b(S[j][r]);
    __syncthreads();

    // O += P V   (B operand from V^T tile: lane n -> h row, contiguous s)
#pragma unroll
    for (int ks = 0; ks < 2; ++ks) {
      short8 pa = *reinterpret_cast<const short8*>(&Ps[(w * 16 + n16) * 72 + ks * 32 + quad * 8]);
#pragma unroll
      for (int j = 0; j < 4; ++j) {
        short8 vb = *reinterpret_cast<const short8*>(&Vs[(j * 16 + n16) * 72 + ks * 32 + quad * 8]);
        O[j] = __builtin_amdgcn_mfma_f32_16x16x32_bf16(pa, vb, O[j], 0, 0, 0);
      }
    }
  }

  // epilogue: O /= l, store fp32
#pragma unroll
  for (int r = 0; r < 4; ++r) {
    float inv = 1.0f / l_i[r];
    int rowl = w * 16 + quad * 4 + r;
#pragma unroll
    for (int j = 0; j < 4; ++j)
      op[(size_t)(g0 + rowl) * 64 + j * 16 + n16] = O[j][r] * inv;
  }
}

// ---------------------------------------------------------------------------
extern "C" void kernel_launch(void* const* d_in, const int* in_sizes, int n_in,
                              void* d_out, int out_size, void* d_ws, size_t ws_size,
                              hipStream_t stream) {
  const float* x  = (const float*)d_in[0];  // [8][4096][512] fp32
  const float* Wq = (const float*)d_in[1];  // [512][64] fp32
  const float* Wk = (const float*)d_in[2];
  const float* Wv = (const float*)d_in[3];

  unsigned short* ws = (unsigned short*)d_ws;
  unsigned short* Wt = ws;                   // 3*64*512      =   98304 elems (bf16)
  unsigned short* qb = ws + 131072;          // 32768*64      = 2097152 each
  unsigned short* kb = qb + 2097152;
  unsigned short* vb = kb + 2097152;         // total ~12.8 MB of ws

  wtrans<<<dim3(128, 3), 256, 0, stream>>>(Wq, Wk, Wv, Wt);
  proj<<<512, 256, 0, stream>>>(x, Wt, qb, kb, vb);
  attn<<<512, 256, 0, stream>>>(qb, kb, vb, (float*)d_out);
}